// Round 5
// baseline (294.974 us; speedup 1.0000x reference)
//
#include <hip/hip_runtime.h>
#include <math.h>

#define JT 64                // j per block (LDS staged)
#define ITILE 1024           // i per block (4 per thread, 256 threads)
#define T8 8                 // 1024-tiles per dimension
#define JCH 16               // 64-j chunks per 1024-tile
#define NJOB_AB 1024         // 8 i-tiles * 128 j-chunks
#define NJOB_TRI 576         // 36 tri-tiles * 16 chunks
#define NBLK (NJOB_AB + 2 * NJOB_TRI)  // 2176
#define NPREP 64             // prep blocks (16384 pts / 256)
#define MAGIC 0x13579BDFu
#define L2E 1.4426950408889634f

// single-instruction transcendentals (libm fallback suspected of 2.5x VALU)
__device__ inline float fexp2(float x) {
  float r;
  asm volatile("v_exp_f32 %0, %1" : "=v"(r) : "v"(x));
  return r;
}
__device__ inline float fsqrt(float x) {
  float r;
  asm volatile("v_sqrt_f32 %0, %1" : "=v"(r) : "v"(x));
  return r;
}

__device__ inline double wred_d(double v) {
#pragma unroll
  for (int o = 32; o > 0; o >>= 1) v += __shfl_down(v, o, 64);
  return v;
}

__device__ inline double bred(double v, double* sm) {
  v = wred_d(v);
  __syncthreads();
  if ((threadIdx.x & 63) == 0) sm[threadIdx.x >> 6] = v;
  __syncthreads();
  return sm[0] + sm[1] + sm[2] + sm[3];
}

// wave 0: reduce 64 prep slots -> smean[8] = {Sb,Qb,Mxb,Myb,St,Qt,Mxt,Myt}
__device__ inline void slot_reduce(const double* slot, double* smean) {
  if (threadIdx.x < 64) {
    int l = threadIdx.x;
    const double* sl = slot + l * 4;
#pragma unroll
    for (int c = 0; c < 4; ++c) {
      double v = sl[c];
      double vb = (l < 32) ? v : 0.0;
      double vt = (l < 32) ? 0.0 : v;
      vb = wred_d(vb);
      vt = wred_d(vt);
      if (l == 0) {
        smean[c] = vb;
        smean[4 + c] = vt;
      }
    }
  }
}

template <bool AB, bool FAST>
__device__ inline void tile_loop(const float4* sj4, const float2* snb2,
                                 const float xi2[4], const float yi2[4],
                                 const float mqi[4], const float alb[4],
                                 float rr0, float rr1, float acc[4][3],
                                 float& sdo, float& sqo) {
  float sd = 0.f, sq = 0.f;
#pragma unroll 2
  for (int jj = 0; jj < JT / 2; ++jj) {
    float4 f0 = sj4[2 * jj];
    float4 f1 = sj4[2 * jj + 1];
    float nb[2];
    if constexpr (AB) {
      float2 nbv = snb2[jj];
      nb[0] = nbv.x;
      nb[1] = nbv.y;
    }
    const float4 fs[2] = {f0, f1};
#pragma unroll
    for (int q = 0; q < 2; ++q) {
      float xj = fs[q].x, yj = fs[q].y, mqj = fs[q].z, uj = fs[q].w;
#pragma unroll
      for (int i = 0; i < 4; ++i) {
        float c = mqi[i] + mqj;
        float arg = fmaf(xi2[i], xj, fmaf(yi2[i], yj, c));  // = -s (scaled)
        float k2 = fexp2(arg);
        float k0, k1;
        if constexpr (FAST) {
          float t = k2 * k2;
          k1 = t * t;       // k2^4  (sigma ratio 1:2)
          float t1 = k1 * k1;
          k0 = t1 * t1;     // k2^16 (sigma ratio 1:4)
        } else {
          k1 = fexp2(arg * rr1);
          k0 = fexp2(arg * rr0);
        }
        acc[i][0] = fmaf(uj, k0, acc[i][0]);
        acc[i][1] = fmaf(uj, k1, acc[i][1]);
        acc[i][2] = fmaf(uj, k2, acc[i][2]);
        if constexpr (AB) {
          // uncentered scaled d2 = al_i + nb_j - (-s); clamp vs cancellation
          float d2u = fmaxf((alb[i] + nb[q]) - arg, 0.f);
          sd += fsqrt(d2u);
          sq += d2u;
        }
      }
    }
  }
  sdo = sd;
  sqo = sq;
}

__global__ __launch_bounds__(256) void fused_kernel(
    const float* __restrict__ base, const float* __restrict__ target,
    const float* __restrict__ log_sigmas, const float* __restrict__ log_scale,
    const float* __restrict__ w1, const float* __restrict__ b1,
    const float* __restrict__ w2, const float* __restrict__ b2,
    const float* __restrict__ g_w1, const float* __restrict__ g_b1,
    const float* __restrict__ g_w2, const float* __restrict__ g_b2,
    const float* __restrict__ bias, float4* __restrict__ pxyu,
    double* __restrict__ slot, double* __restrict__ paa,
    double* __restrict__ pbb, double* __restrict__ pab,
    double* __restrict__ psd, double* __restrict__ psq,
    unsigned* __restrict__ flags, unsigned* __restrict__ fctr,
    float* __restrict__ out, int n) {
  __shared__ __align__(16) float4 sj4[JT];
  __shared__ __align__(16) float snb[JT];
  __shared__ double sm[4];
  __shared__ double smean[8];
  __shared__ int lastf;

  int b = blockIdx.x;
  int tid = threadIdx.x;

  float s2 = __expf(log_sigmas[2]);
  float r2 = __fsqrt_rn(L2E / (2.f * s2 * s2));  // coord pre-scale (band 2)

  // ---------- phase 1: prep (blocks 0..63 only) ----------
  if (b < NPREP) {
    int gid = b * 256 + tid;
    int isT = gid >= n;  // block-uniform
    const float* pts = isT ? target : base;
    int idx = isT ? gid - n : gid;
    float ex = __expf(log_scale[0]);
    float ey = __expf(log_scale[1]);
    float2 p = ((const float2*)pts)[idx];
    float xr = p.x * ex, yr = p.y * ey;  // MLP input space
    float logit = b2[0];
#pragma unroll
    for (int k = 0; k < 32; ++k) {
      float h = fmaf(xr, w1[k], fmaf(yr, w1[32 + k], b1[k]));
      h = fmaxf(h, 0.f);
      logit = fmaf(h, w2[k], logit);
    }
    float u = fmaxf(logit, 0.f) + log1pf(__expf(-fabsf(logit))) + 1e-6f;
    float X = xr * r2, Y = yr * r2;
    float mq = -fmaf(X, X, Y * Y);
    pxyu[gid] = make_float4(X, Y, mq, u);
    double su = bred((double)u, sm);
    double qu = bred((double)u * (double)u, sm);
    double mx = bred((double)u * (double)X, sm);
    double my = bred((double)u * (double)Y, sm);
    if (tid == 0) {
      double* s = slot + b * 4;
      s[0] = su;
      s[1] = qu;
      s[2] = mx;
      s[3] = my;
      if (b == 0) *fctr = 0u;  // before release fence -> visible pre-flag
      __threadfence();         // release prep data
      __hip_atomic_store(&flags[b], MAGIC, __ATOMIC_RELAXED,
                         __HIP_MEMORY_SCOPE_AGENT);
    }
  }

  // ---------- phase 2: wait for all prep flags ----------
  {
    const unsigned* f = flags;
    int l = tid & 63;
    while (__hip_atomic_load(&f[l], __ATOMIC_RELAXED,
                             __HIP_MEMORY_SCOPE_AGENT) != MAGIC)
      __builtin_amdgcn_s_sleep(2);
    __syncthreads();
    __threadfence();  // acquire prep data
  }

  // ---------- phase 3: pair tile job ----------
  int m, it, jt = 0, j0, pidx;
  if (b < NJOB_AB) {  // AB first (heavier); light tri jobs drain last
    m = 2;
    pidx = b;
    it = b >> 7;
    j0 = (b & 127) * JT;
  } else {
    int r = b - NJOB_AB;
    m = (r < NJOB_TRI) ? 0 : 1;
    if (m == 1) r -= NJOB_TRI;
    pidx = r;
    int tile = r >> 4;
    int q = r & 15;
    int idx = tile, len = T8;
    it = 0;
    while (idx >= len) {
      idx -= len;
      --len;
      ++it;
    }
    jt = it + idx;
    j0 = jt * ITILE + q * JT;
  }
  const float4* pI = pxyu + ((m == 1) ? n : 0);
  const float4* pJ = pxyu + ((m == 0) ? 0 : n);

  float cx = 0.f, cy = 0.f, cx2 = 0.f, cy2 = 0.f, cc = 0.f;
  if (m == 2) {
    slot_reduce(slot, smean);  // wave 0; consumed after barrier below
  }

  float s0 = __expf(log_sigmas[0]);
  float s1 = __expf(log_sigmas[1]);
  float rr0 = (s2 * s2) / (s0 * s0);
  float rr1 = (s2 * s2) / (s1 * s1);
  bool fast = (fabsf(rr0 - 16.f) <= 0.016f) && (fabsf(rr1 - 4.f) <= 0.004f);

  if (m == 2) {
    __syncthreads();
    cx = (float)(smean[2] / smean[0] - smean[6] / smean[4]);
    cy = (float)(smean[3] / smean[0] - smean[7] / smean[4]);
    cx2 = 2.f * cx;
    cy2 = 2.f * cy;
    cc = cx * cx + cy * cy;
  }

  if (tid < JT) {
    float4 v = pJ[j0 + tid];  // raw coords; AB j-side q stays raw
    sj4[tid] = v;
    if (m == 2) snb[tid] = -fmaf(cx2, v.x, cy2 * v.y);  // -beta_j
  }
  __syncthreads();

  int i0 = it * ITILE + tid;
  float xi2[4], yi2[4], mqi[4], u[4], alb[4];
#pragma unroll
  for (int i = 0; i < 4; ++i) {
    float4 P = pI[i0 + i * 256];
    u[i] = P.w;
    if (m == 2) {  // shift i-side by c = mean_b - mean_t
      float xc = P.x - cx, yc = P.y - cy;
      xi2[i] = 2.f * xc;
      yi2[i] = 2.f * yc;
      mqi[i] = -fmaf(xc, xc, yc * yc);
      alb[i] = fmaf(cx2, xc, cy2 * yc) + cc;  // al_i
    } else {
      xi2[i] = 2.f * P.x;
      yi2[i] = 2.f * P.y;
      mqi[i] = P.z;
      alb[i] = 0.f;
    }
  }

  float accf[4][3] = {};
  float sd = 0.f, sq = 0.f;
  const float2* snb2 = reinterpret_cast<const float2*>(snb);
  if (m == 2) {
    if (fast)
      tile_loop<true, true>(sj4, snb2, xi2, yi2, mqi, alb, rr0, rr1, accf, sd,
                            sq);
    else
      tile_loop<true, false>(sj4, snb2, xi2, yi2, mqi, alb, rr0, rr1, accf,
                             sd, sq);
  } else {
    if (fast)
      tile_loop<false, true>(sj4, snb2, xi2, yi2, mqi, alb, rr0, rr1, accf,
                             sd, sq);
    else
      tile_loop<false, false>(sj4, snb2, xi2, yi2, mqi, alb, rr0, rr1, accf,
                              sd, sq);
  }

  double wgt = (m != 2 && jt != it) ? 2.0 : 1.0;  // symmetric off-diag tiles
  double c0 = 0.0, c1 = 0.0, c2 = 0.0;
#pragma unroll
  for (int i = 0; i < 4; ++i) {
    c0 += (double)u[i] * accf[i][0];
    c1 += (double)u[i] * accf[i][1];
    c2 += (double)u[i] * accf[i][2];
  }
  double r0 = bred(c0, sm) * wgt;
  double r1 = bred(c1, sm) * wgt;
  double r2d = bred(c2, sm) * wgt;
  double* prow = (m == 0) ? paa : (m == 1) ? pbb : pab;
  int stride = (m == 2) ? NJOB_AB : NJOB_TRI;
  if (tid == 0) {
    prow[0 * stride + pidx] = r0;
    prow[1 * stride + pidx] = r1;
    prow[2 * stride + pidx] = r2d;
  }
  if (m == 2) {
    double rsd = bred((double)sd, sm);
    double rsq = bred((double)sq, sm);
    if (tid == 0) {
      psd[pidx] = rsd;
      psq[pidx] = rsq;
    }
  }

  // ---------- phase 4: last-block final reduction ----------
  if (tid == 0) {
    __threadfence();
    unsigned old = atomicAdd(fctr, 1u);
    lastf = (old == NBLK - 1) ? 1 : 0;
  }
  __syncthreads();
  if (!lastf) return;
  __threadfence();

  slot_reduce(slot, smean);
  __syncthreads();
  int t = tid;
  double vaa[3], vbb[3], vab[3];
  for (int s = 0; s < 3; ++s) {
    const double* pa = paa + s * NJOB_TRI;
    const double* pb = pbb + s * NJOB_TRI;
    const double* pc = pab + s * NJOB_AB;
    double va = pa[t] + pa[t + 256] + ((t < 64) ? pa[t + 512] : 0.0);
    double vb = pb[t] + pb[t + 256] + ((t < 64) ? pb[t + 512] : 0.0);
    double vc = pc[t] + pc[t + 256] + pc[t + 512] + pc[t + 768];
    vaa[s] = bred(va, sm);
    vbb[s] = bred(vb, sm);
    vab[s] = bred(vc, sm);
  }
  double sdt = bred(psd[t] + psd[t + 256] + psd[t + 512] + psd[t + 768], sm);
  double sqt = bred(psq[t] + psq[t + 256] + psq[t + 512] + psq[t + 768], sm);

  if (tid == 0) {
    double Sb = smean[0], Qb = smean[1], St = smean[4], Qt = smean[5];
    double pband[3];
    for (int s = 0; s < 3; ++s)
      pband[s] = vaa[s] / (Sb * Sb) + vbb[s] / (St * St) -
                 2.0 * vab[s] / (Sb * St);
    double s2d = (double)s2;
    double r2sq = (double)L2E / (2.0 * s2d * s2d);
    double sd_real = sdt / sqrt(r2sq);
    double sq_real = sqt / r2sq;
    double NN = (double)n;
    double NM = NN * NN;
    double mean_d = sd_real / NM;
    double var_d = (sq_real - sd_real * sd_real / NM) / (NM - 1.0);
    double wv = (Qb / (Sb * Sb) - 1.0 / NN) / (NN - 1.0) +
                (Qt / (St * St) - 1.0 / NN) / (NN - 1.0);
    float st[4] = {(float)mean_d, (float)var_d, 0.f, (float)wv};
    float gl[3] = {g_b2[0], g_b2[1], g_b2[2]};
    for (int k = 0; k < 32; ++k) {
      float h = g_b1[k];
      for (int c = 0; c < 4; ++c) h = fmaf(st[c], g_w1[c * 32 + k], h);
      h = fmaxf(h, 0.f);
      for (int s = 0; s < 3; ++s) gl[s] = fmaf(h, g_w2[k * 3 + s], gl[s]);
    }
    float gw[3];
    float gsum = 0.f;
    for (int s = 0; s < 3; ++s) {
      gw[s] = fmaxf(gl[s], 0.f) + log1pf(__expf(-fabsf(gl[s])));
      gsum += gw[s];
    }
    double r = 0.0;
    for (int s = 0; s < 3; ++s) r += (double)(gw[s] / gsum) * pband[s];
    out[0] = (float)(r + (double)bias[0]);
  }
}

extern "C" void kernel_launch(void* const* d_in, const int* in_sizes, int n_in,
                              void* d_out, int out_size, void* d_ws,
                              size_t ws_size, hipStream_t stream) {
  const float* base = (const float*)d_in[0];
  const float* target = (const float*)d_in[1];
  const float* log_sigmas = (const float*)d_in[2];
  const float* log_scale = (const float*)d_in[3];
  const float* wn_w1 = (const float*)d_in[4];
  const float* wn_b1 = (const float*)d_in[5];
  const float* wn_w2 = (const float*)d_in[6];
  const float* wn_b2 = (const float*)d_in[7];
  const float* g_w1 = (const float*)d_in[8];
  const float* g_b1 = (const float*)d_in[9];
  const float* g_w2 = (const float*)d_in[10];
  const float* g_b2 = (const float*)d_in[11];
  const float* bias = (const float*)d_in[12];
  int n = in_sizes[0] / 2;  // 8192

  double* dbase = (double*)d_ws;
  double* slot = dbase;                // 64*4   = 256
  double* paa = dbase + 256;           // 3*576
  double* pbb = paa + 3 * NJOB_TRI;    // 3*576
  double* pab = pbb + 3 * NJOB_TRI;    // 3*1024
  double* psd = pab + 3 * NJOB_AB;     // 1024
  double* psq = psd + NJOB_AB;         // 1024
  double* dend = psq + NJOB_AB;        // total 8832 doubles (16B-aligned end)
  float4* pxyu = (float4*)dend;        // 2n float4
  unsigned* flags = (unsigned*)(pxyu + 2 * n);  // 64
  unsigned* fctr = flags + NPREP;

  fused_kernel<<<NBLK, 256, 0, stream>>>(
      base, target, log_sigmas, log_scale, wn_w1, wn_b1, wn_w2, wn_b2, g_w1,
      g_b1, g_w2, g_b2, bias, pxyu, slot, paa, pbb, pab, psd, psq, flags,
      fctr, (float*)d_out, n);
}

// Round 6
// 186.288 us; speedup vs baseline: 1.5834x; 1.5834x over previous
//
#include <hip/hip_runtime.h>
#include <math.h>

#define JT 64                // j per block (LDS staged)
#define ITILE 512            // i per block (2 per thread, 256 threads)
#define T16 16               // 512-tiles per dimension
#define NJOB_AB 2048         // 16 i-tiles * 128 j-chunks
#define NJOB_TRI 1088        // 136 tri-tiles * 8 chunks
#define NBLK (NJOB_AB + 2 * NJOB_TRI)  // 4224
#define L2E 1.4426950408889634f

// single-instruction transcendentals; NON-volatile so the scheduler may
// reorder/interleave them (R5's `asm volatile` serialized all exps: 23% busy)
__device__ inline float fexp2(float x) {
  float r;
  asm("v_exp_f32 %0, %1" : "=v"(r) : "v"(x));
  return r;
}
__device__ inline float fsqrt(float x) {
  float r;
  asm("v_sqrt_f32 %0, %1" : "=v"(r) : "v"(x));
  return r;
}

__device__ inline double wred_d(double v) {
#pragma unroll
  for (int o = 32; o > 0; o >>= 1) v += __shfl_down(v, o, 64);
  return v;
}

__device__ inline double bred(double v, double* sm) {
  v = wred_d(v);
  __syncthreads();
  if ((threadIdx.x & 63) == 0) sm[threadIdx.x >> 6] = v;
  __syncthreads();
  return sm[0] + sm[1] + sm[2] + sm[3];
}

// wave 0: reduce 64 prep slots -> smean[8] = {Sb,Qb,Mxb,Myb,St,Qt,Mxt,Myt}
__device__ inline void slot_reduce(const double* slot, double* smean) {
  if (threadIdx.x < 64) {
    int l = threadIdx.x;
    const double* sl = slot + l * 4;
#pragma unroll
    for (int c = 0; c < 4; ++c) {
      double v = sl[c];
      double vb = (l < 32) ? v : 0.0;
      double vt = (l < 32) ? 0.0 : v;
      vb = wred_d(vb);
      vt = wred_d(vt);
      if (l == 0) {
        smean[c] = vb;
        smean[4 + c] = vt;
      }
    }
  }
}

__global__ __launch_bounds__(256) void prep_kernel(
    const float* __restrict__ base, const float* __restrict__ target,
    const float* __restrict__ log_sigmas, const float* __restrict__ log_scale,
    const float* __restrict__ w1, const float* __restrict__ b1,
    const float* __restrict__ w2, const float* __restrict__ b2,
    float2* __restrict__ pxy, float* __restrict__ pu,
    double* __restrict__ slot, unsigned* __restrict__ fctr, int n) {
  __shared__ double sm[4];
  int gid = blockIdx.x * 256 + threadIdx.x;
  int isT = gid >= n;  // uniform per block (n % 256 == 0)
  const float* pts = isT ? target : base;
  int idx = isT ? gid - n : gid;
  float ex = __expf(log_scale[0]);
  float ey = __expf(log_scale[1]);
  float s2 = __expf(log_sigmas[2]);
  float r2 = __fsqrt_rn(L2E / (2.f * s2 * s2));  // coord pre-scale, band 2
  float2 p = ((const float2*)pts)[idx];
  float xr = p.x * ex, yr = p.y * ey;  // MLP input space (no r2!)
  float logit = b2[0];
#pragma unroll
  for (int k = 0; k < 32; ++k) {
    float h = fmaf(xr, w1[k], fmaf(yr, w1[32 + k], b1[k]));
    h = fmaxf(h, 0.f);
    logit = fmaf(h, w2[k], logit);
  }
  float u = fmaxf(logit, 0.f) + log1pf(__expf(-fabsf(logit))) + 1e-6f;
  float X = xr * r2, Y = yr * r2;
  pxy[gid] = make_float2(X, Y);
  pu[gid] = u;
  double su = bred((double)u, sm);
  double qu = bred((double)u * (double)u, sm);
  double mx = bred((double)u * (double)X, sm);
  double my = bred((double)u * (double)Y, sm);
  if (threadIdx.x == 0) {
    double* s = slot + blockIdx.x * 4;
    s[0] = su;
    s[1] = qu;
    s[2] = mx;
    s[3] = my;
    if (blockIdx.x == 0) *fctr = 0u;
  }
}

template <bool AB, bool FAST>
__device__ inline void tile_loop(const float4* sxy4, const float2* su2,
                                 const float2* sb2, const float x[2],
                                 const float y[2], const float al[2],
                                 float rr0, float rr1, float acc[2][3],
                                 float& sdo, float& sqo) {
  float sd = 0.f, sq = 0.f;
#pragma unroll 2
  for (int jj = 0; jj < JT / 2; ++jj) {
    float4 xy = sxy4[jj];  // {x0,y0,x1,y1} two j points (LDS broadcast)
    float2 u2 = su2[jj];
    float bj[2];
    if constexpr (AB) {
      float2 b2v = sb2[jj];
      bj[0] = b2v.x;
      bj[1] = b2v.y;
    }
    float xj[2] = {xy.x, xy.z};
    float yj[2] = {xy.y, xy.w};
    float uj[2] = {u2.x, u2.y};
#pragma unroll
    for (int q = 0; q < 2; ++q) {
#pragma unroll
      for (int i = 0; i < 2; ++i) {
        float dx = x[i] - xj[q];
        float dy = y[i] - yj[q];
        // arg = -(dx^2+dy^2) built with free neg modifiers (no v_xor)
        float arg = fmaf(-dx, dx, -dy * dy);  // = -d2_centered * ln2e/2s2^2
        float k2 = fexp2(arg);
        float k0, k1;
        if constexpr (FAST) {
          float t = k2 * k2;
          k1 = t * t;  // k2^4  (sigma ratio 1:2)
          float t1 = k1 * k1;
          k0 = t1 * t1;  // k2^16 (sigma ratio 1:4)
        } else {
          k1 = fexp2(arg * rr1);
          k0 = fexp2(arg * rr0);
        }
        acc[i][0] = fmaf(uj[q], k0, acc[i][0]);
        acc[i][1] = fmaf(uj[q], k1, acc[i][1]);
        acc[i][2] = fmaf(uj[q], k2, acc[i][2]);
        if constexpr (AB) {
          // uncentered scaled d2 = -arg + al_i - bj ; clamp vs cancellation
          float d2u = fmaxf((al[i] - arg) - bj[q], 0.f);
          sd += fsqrt(d2u);
          sq += d2u;
        }
      }
    }
  }
  sdo = sd;
  sqo = sq;
}

__global__ __launch_bounds__(256) void pair_kernel(
    const float2* __restrict__ pxy, const float* __restrict__ pu,
    const double* __restrict__ slot, double* __restrict__ paa,
    double* __restrict__ pbb, double* __restrict__ pab,
    double* __restrict__ psd, double* __restrict__ psq,
    unsigned* __restrict__ fctr, const float* __restrict__ log_sigmas,
    const float* __restrict__ g_w1, const float* __restrict__ g_b1,
    const float* __restrict__ g_w2, const float* __restrict__ g_b2,
    const float* __restrict__ bias, float* __restrict__ out, int n) {
  __shared__ __align__(16) float2 sxy[JT];
  __shared__ __align__(16) float su[JT];
  __shared__ __align__(16) float sb[JT];
  __shared__ double sm[4];
  __shared__ double smean[8];
  __shared__ int lastf;

  int b = blockIdx.x;
  int m, it, jt = 0, j0, pidx;
  if (b < NJOB_AB) {  // AB first (heavier), light tri jobs drain last
    m = 2;
    pidx = b;
    it = b >> 7;          // 16 i-tiles
    j0 = (b & 127) * JT;  // 128 j-chunks
  } else {
    int r = b - NJOB_AB;
    m = (r < NJOB_TRI) ? 0 : 1;
    if (m == 1) r -= NJOB_TRI;
    pidx = r;
    int tile = r >> 3;  // 8 chunks per 512-tile
    int q = r & 7;
    int idx = tile, len = T16;
    it = 0;
    while (idx >= len) {
      idx -= len;
      --len;
      ++it;
    }
    jt = it + idx;
    j0 = jt * ITILE + q * JT;
  }
  const float2* pxyI = pxy + ((m == 1) ? n : 0);
  const float* puI = pu + ((m == 1) ? n : 0);
  const float2* pxyJ = pxy + ((m == 0) ? 0 : n);
  const float* puJ = pu + ((m == 0) ? 0 : n);

  float cx = 0.f, cy = 0.f, cx2 = 0.f, cy2 = 0.f, cc = 0.f;
  if (m == 2) {
    slot_reduce(slot, smean);  // wave 0; consumed after the barrier below
  }

  float s0 = __expf(log_sigmas[0]);
  float s1 = __expf(log_sigmas[1]);
  float s2 = __expf(log_sigmas[2]);
  float rr0 = (s2 * s2) / (s0 * s0);
  float rr1 = (s2 * s2) / (s1 * s1);
  bool fast = (fabsf(rr0 - 16.f) <= 0.016f) && (fabsf(rr1 - 4.f) <= 0.004f);

  if (m == 2) {
    __syncthreads();
    cx = (float)(smean[2] / smean[0] - smean[6] / smean[4]);
    cy = (float)(smean[3] / smean[0] - smean[7] / smean[4]);
    cx2 = 2.f * cx;
    cy2 = 2.f * cy;
    cc = cx * cx + cy * cy;
  }

  if (threadIdx.x < JT) {
    float2 v = pxyJ[j0 + threadIdx.x];
    sxy[threadIdx.x] = v;
    su[threadIdx.x] = puJ[j0 + threadIdx.x];
    if (m == 2) sb[threadIdx.x] = fmaf(cx2, v.x, cy2 * v.y);  // beta_j
  }
  __syncthreads();

  int i0 = it * ITILE + threadIdx.x;
  float x[2], y[2], u[2], al[2];
#pragma unroll
  for (int i = 0; i < 2; ++i) {
    float2 P = pxyI[i0 + i * 256];
    u[i] = puI[i0 + i * 256];
    x[i] = P.x;
    y[i] = P.y;
    al[i] = 0.f;
    if (m == 2) {  // center i-side; alpha recovers uncentered distance
      x[i] -= cx;
      y[i] -= cy;
      al[i] = fmaf(cx2, x[i], cy2 * y[i]) + cc;
    }
  }

  float accf[2][3] = {};
  float sd = 0.f, sq = 0.f;
  const float4* sxy4 = reinterpret_cast<const float4*>(sxy);
  const float2* su2 = reinterpret_cast<const float2*>(su);
  const float2* sb2 = reinterpret_cast<const float2*>(sb);
  if (m == 2) {
    if (fast)
      tile_loop<true, true>(sxy4, su2, sb2, x, y, al, rr0, rr1, accf, sd, sq);
    else
      tile_loop<true, false>(sxy4, su2, sb2, x, y, al, rr0, rr1, accf, sd, sq);
  } else {
    if (fast)
      tile_loop<false, true>(sxy4, su2, sb2, x, y, al, rr0, rr1, accf, sd, sq);
    else
      tile_loop<false, false>(sxy4, su2, sb2, x, y, al, rr0, rr1, accf, sd,
                              sq);
  }

  double wgt = (m != 2 && jt != it) ? 2.0 : 1.0;  // symmetric off-diag tiles
  double c0 = 0.0, c1 = 0.0, c2 = 0.0;
#pragma unroll
  for (int i = 0; i < 2; ++i) {
    c0 += (double)u[i] * accf[i][0];
    c1 += (double)u[i] * accf[i][1];
    c2 += (double)u[i] * accf[i][2];
  }
  double r0 = bred(c0, sm) * wgt;
  double r1 = bred(c1, sm) * wgt;
  double r2d = bred(c2, sm) * wgt;
  double* prow = (m == 0) ? paa : (m == 1) ? pbb : pab;
  int stride = (m == 2) ? NJOB_AB : NJOB_TRI;
  if (threadIdx.x == 0) {
    prow[0 * stride + pidx] = r0;
    prow[1 * stride + pidx] = r1;
    prow[2 * stride + pidx] = r2d;
  }
  if (m == 2) {
    double rsd = bred((double)sd, sm);
    double rsq = bred((double)sq, sm);
    if (threadIdx.x == 0) {
      psd[pidx] = rsd;
      psq[pidx] = rsq;
    }
  }

  // ---- last-block final reduction (ticket + device fence) ----
  if (threadIdx.x == 0) {
    __threadfence();
    unsigned old = atomicAdd(fctr, 1u);
    lastf = (old == NBLK - 1) ? 1 : 0;
  }
  __syncthreads();
  if (!lastf) return;
  __threadfence();

  slot_reduce(slot, smean);
  __syncthreads();
  int t = threadIdx.x;
  double vaa[3], vbb[3], vab[3];
  for (int s = 0; s < 3; ++s) {
    const double* pa = paa + s * NJOB_TRI;
    const double* pb = pbb + s * NJOB_TRI;
    const double* pc = pab + s * NJOB_AB;
    double va = pa[t] + pa[t + 256] + pa[t + 512] + pa[t + 768] +
                ((t < 64) ? pa[t + 1024] : 0.0);
    double vb = pb[t] + pb[t + 256] + pb[t + 512] + pb[t + 768] +
                ((t < 64) ? pb[t + 1024] : 0.0);
    double vc = 0.0;
#pragma unroll
    for (int k = 0; k < 8; ++k) vc += pc[t + 256 * k];
    vaa[s] = bred(va, sm);
    vbb[s] = bred(vb, sm);
    vab[s] = bred(vc, sm);
  }
  double sdp = 0.0, sqp = 0.0;
#pragma unroll
  for (int k = 0; k < 8; ++k) {
    sdp += psd[t + 256 * k];
    sqp += psq[t + 256 * k];
  }
  double sdt = bred(sdp, sm);
  double sqt = bred(sqp, sm);

  if (threadIdx.x == 0) {
    double Sb = smean[0], Qb = smean[1], St = smean[4], Qt = smean[5];
    double pband[3];
    for (int s = 0; s < 3; ++s)
      pband[s] = vaa[s] / (Sb * Sb) + vbb[s] / (St * St) -
                 2.0 * vab[s] / (Sb * St);
    double s2d = (double)s2;
    double r2sq = (double)L2E / (2.0 * s2d * s2d);
    double sd_real = sdt / sqrt(r2sq);
    double sq_real = sqt / r2sq;
    double NN = (double)n;
    double NM = NN * NN;
    double mean_d = sd_real / NM;
    double var_d = (sq_real - sd_real * sd_real / NM) / (NM - 1.0);
    double wv = (Qb / (Sb * Sb) - 1.0 / NN) / (NN - 1.0) +
                (Qt / (St * St) - 1.0 / NN) / (NN - 1.0);
    float st[4] = {(float)mean_d, (float)var_d, 0.f, (float)wv};
    float gl[3] = {g_b2[0], g_b2[1], g_b2[2]};
    for (int k = 0; k < 32; ++k) {
      float h = g_b1[k];
      for (int c = 0; c < 4; ++c) h = fmaf(st[c], g_w1[c * 32 + k], h);
      h = fmaxf(h, 0.f);
      for (int s = 0; s < 3; ++s) gl[s] = fmaf(h, g_w2[k * 3 + s], gl[s]);
    }
    float gw[3];
    float gsum = 0.f;
    for (int s = 0; s < 3; ++s) {
      gw[s] = fmaxf(gl[s], 0.f) + log1pf(__expf(-fabsf(gl[s])));
      gsum += gw[s];
    }
    double r = 0.0;
    for (int s = 0; s < 3; ++s) r += (double)(gw[s] / gsum) * pband[s];
    out[0] = (float)(r + (double)bias[0]);
  }
}

extern "C" void kernel_launch(void* const* d_in, const int* in_sizes, int n_in,
                              void* d_out, int out_size, void* d_ws,
                              size_t ws_size, hipStream_t stream) {
  const float* base = (const float*)d_in[0];
  const float* target = (const float*)d_in[1];
  const float* log_sigmas = (const float*)d_in[2];
  const float* log_scale = (const float*)d_in[3];
  const float* wn_w1 = (const float*)d_in[4];
  const float* wn_b1 = (const float*)d_in[5];
  const float* wn_w2 = (const float*)d_in[6];
  const float* wn_b2 = (const float*)d_in[7];
  const float* g_w1 = (const float*)d_in[8];
  const float* g_b1 = (const float*)d_in[9];
  const float* g_w2 = (const float*)d_in[10];
  const float* g_b2 = (const float*)d_in[11];
  const float* bias = (const float*)d_in[12];
  int n = in_sizes[0] / 2;  // 8192

  double* dbase = (double*)d_ws;
  double* slot = dbase;                // 64*4 = 256
  double* paa = dbase + 256;           // 3*1088
  double* pbb = paa + 3 * NJOB_TRI;    // 3*1088
  double* pab = pbb + 3 * NJOB_TRI;    // 3*2048
  double* psd = pab + 3 * NJOB_AB;     // 2048
  double* psq = psd + NJOB_AB;         // 2048
  double* dend = psq + NJOB_AB;
  float2* pxy = (float2*)dend;         // 2n
  float* pu = (float*)(pxy + 2 * n);   // 2n
  unsigned* fctr = (unsigned*)(pu + 2 * n);

  prep_kernel<<<(2 * n) / 256, 256, 0, stream>>>(
      base, target, log_sigmas, log_scale, wn_w1, wn_b1, wn_w2, wn_b2, pxy, pu,
      slot, fctr, n);
  pair_kernel<<<NBLK, 256, 0, stream>>>(pxy, pu, slot, paa, pbb, pab, psd, psq,
                                        fctr, log_sigmas, g_w1, g_b1, g_w2,
                                        g_b2, bias, (float*)d_out, n);
}

// Round 7
// 147.565 us; speedup vs baseline: 1.9989x; 1.2624x over previous
//
#include <hip/hip_runtime.h>
#include <math.h>

#define JT 64                // j per block (LDS staged)
#define ITILE 1024           // i per block (4 per thread, 256 threads)
#define T8 8                 // 1024-tiles per dimension
#define NJOB_AB 1024         // 8 i-tiles * 128 j-chunks
#define NJOB_TRI 576         // 36 tri-tiles * 16 chunks
#define NBLK (NJOB_AB + 2 * NJOB_TRI)  // 2176
#define L2E 1.4426950408889634f

typedef float v2f __attribute__((ext_vector_type(2)));

// exp2(-x) in ONE instruction: neg folded into VOP3 input modifier.
__device__ inline float fexp2n(float x) {
  float r;
  asm("v_exp_f32 %0, -%1" : "=v"(r) : "v"(x));
  return r;
}
__device__ inline float fsqrt(float x) {
  float r;
  asm("v_sqrt_f32 %0, %1" : "=v"(r) : "v"(x));
  return r;
}

__device__ inline double wred_d(double v) {
#pragma unroll
  for (int o = 32; o > 0; o >>= 1) v += __shfl_down(v, o, 64);
  return v;
}

__device__ inline double bred(double v, double* sm) {
  v = wred_d(v);
  __syncthreads();
  if ((threadIdx.x & 63) == 0) sm[threadIdx.x >> 6] = v;
  __syncthreads();
  return sm[0] + sm[1] + sm[2] + sm[3];
}

// wave 0: reduce 64 prep slots -> smean[8] = {Sb,Qb,Mxb,Myb,St,Qt,Mxt,Myt}
__device__ inline void slot_reduce(const double* slot, double* smean) {
  if (threadIdx.x < 64) {
    int l = threadIdx.x;
    const double* sl = slot + l * 4;
#pragma unroll
    for (int c = 0; c < 4; ++c) {
      double v = sl[c];
      double vb = (l < 32) ? v : 0.0;
      double vt = (l < 32) ? 0.0 : v;
      vb = wred_d(vb);
      vt = wred_d(vt);
      if (l == 0) {
        smean[c] = vb;
        smean[4 + c] = vt;
      }
    }
  }
}

__global__ __launch_bounds__(256) void prep_kernel(
    const float* __restrict__ base, const float* __restrict__ target,
    const float* __restrict__ log_sigmas, const float* __restrict__ log_scale,
    const float* __restrict__ w1, const float* __restrict__ b1,
    const float* __restrict__ w2, const float* __restrict__ b2,
    float2* __restrict__ pxy, float* __restrict__ pu,
    double* __restrict__ slot, unsigned* __restrict__ fctr, int n) {
  __shared__ double sm[4];
  int gid = blockIdx.x * 256 + threadIdx.x;
  int isT = gid >= n;  // uniform per block (n % 256 == 0)
  const float* pts = isT ? target : base;
  int idx = isT ? gid - n : gid;
  float ex = __expf(log_scale[0]);
  float ey = __expf(log_scale[1]);
  float s2 = __expf(log_sigmas[2]);
  float r2 = __fsqrt_rn(L2E / (2.f * s2 * s2));  // coord pre-scale, band 2
  float2 p = ((const float2*)pts)[idx];
  float xr = p.x * ex, yr = p.y * ey;  // MLP input space (no r2!)
  float logit = b2[0];
#pragma unroll
  for (int k = 0; k < 32; ++k) {
    float h = fmaf(xr, w1[k], fmaf(yr, w1[32 + k], b1[k]));
    h = fmaxf(h, 0.f);
    logit = fmaf(h, w2[k], logit);
  }
  float u = fmaxf(logit, 0.f) + log1pf(__expf(-fabsf(logit))) + 1e-6f;
  float X = xr * r2, Y = yr * r2;
  pxy[gid] = make_float2(X, Y);
  pu[gid] = u;
  double su = bred((double)u, sm);
  double qu = bred((double)u * (double)u, sm);
  double mx = bred((double)u * (double)X, sm);
  double my = bred((double)u * (double)Y, sm);
  if (threadIdx.x == 0) {
    double* s = slot + blockIdx.x * 4;
    s[0] = su;
    s[1] = qu;
    s[2] = mx;
    s[3] = my;
    if (blockIdx.x == 0) *fctr = 0u;
  }
}

// Packed-FP32 inner loop: v2f ops -> v_pk_{add,mul,fma}_f32 on CDNA4.
// Pair dimension = the two j points loaded per iteration (SoA LDS).
template <bool AB, bool FAST>
__device__ inline void tile_loop(const float* sx, const float* sy,
                                 const float* su, const float* snb,
                                 const v2f xi2[4], const v2f yi2[4],
                                 const v2f al2[4], float rr0, float rr1,
                                 v2f a0[4], v2f a1[4], v2f a2[4], float& sdo,
                                 float& sqo) {
  float sda = 0.f, sdb = 0.f;
  v2f sq2 = {0.f, 0.f};
  const v2f vz = {0.f, 0.f};
#pragma unroll 2
  for (int jj = 0; jj < JT / 2; ++jj) {
    v2f xj = *(const v2f*)&sx[2 * jj];
    v2f yj = *(const v2f*)&sy[2 * jj];
    v2f uj = *(const v2f*)&su[2 * jj];
    v2f nbj;
    if constexpr (AB) nbj = *(const v2f*)&snb[2 * jj];
#pragma unroll
    for (int i = 0; i < 4; ++i) {
      v2f dx = xi2[i] - xj;
      v2f dy = yi2[i] - yj;
      v2f pos = dx * dx + dy * dy;  // contracts to pk_fma; = scaled d2
      v2f k2 = {fexp2n(pos.x), fexp2n(pos.y)};
      v2f k0, k1;
      if constexpr (FAST) {
        v2f t = k2 * k2;
        k1 = t * t;  // k2^4  (sigma ratio 1:2)
        v2f t1 = k1 * k1;
        k0 = t1 * t1;  // k2^16 (sigma ratio 1:4)
      } else {
        v2f m1 = pos * rr1;
        v2f m0 = pos * rr0;
        k1 = {fexp2n(m1.x), fexp2n(m1.y)};
        k0 = {fexp2n(m0.x), fexp2n(m0.y)};
      }
      a0[i] += uj * k0;
      a1[i] += uj * k1;
      a2[i] += uj * k2;
      if constexpr (AB) {
        // uncentered scaled d2 = pos + al_i - bj; clamp vs cancellation
        v2f anb = al2[i] + nbj;
        v2f d2u = pos + anb;
        d2u = __builtin_elementwise_max(d2u, vz);
        sq2 += d2u;
        sda += fsqrt(d2u.x);
        sdb += fsqrt(d2u.y);
      }
    }
  }
  sdo = sda + sdb;
  sqo = sq2.x + sq2.y;
}

__global__ __launch_bounds__(256) void pair_kernel(
    const float2* __restrict__ pxy, const float* __restrict__ pu,
    const double* __restrict__ slot, double* __restrict__ paa,
    double* __restrict__ pbb, double* __restrict__ pab,
    double* __restrict__ psd, double* __restrict__ psq,
    unsigned* __restrict__ fctr, const float* __restrict__ log_sigmas,
    const float* __restrict__ g_w1, const float* __restrict__ g_b1,
    const float* __restrict__ g_w2, const float* __restrict__ g_b2,
    const float* __restrict__ bias, float* __restrict__ out, int n) {
  __shared__ __align__(16) float sx[JT];
  __shared__ __align__(16) float sy[JT];
  __shared__ __align__(16) float su[JT];
  __shared__ __align__(16) float snb[JT];
  __shared__ double sm[4];
  __shared__ double smean[8];
  __shared__ int lastf;

  int b = blockIdx.x;
  int m, it, jt = 0, j0, pidx;
  if (b < NJOB_AB) {  // AB first (heavier), light tri jobs drain last
    m = 2;
    pidx = b;
    it = b >> 7;          // 8 i-tiles
    j0 = (b & 127) * JT;  // 128 j-chunks
  } else {
    int r = b - NJOB_AB;
    m = (r < NJOB_TRI) ? 0 : 1;
    if (m == 1) r -= NJOB_TRI;
    pidx = r;
    int tile = r >> 4;
    int q = r & 15;
    int idx = tile, len = T8;
    it = 0;
    while (idx >= len) {
      idx -= len;
      --len;
      ++it;
    }
    jt = it + idx;
    j0 = jt * ITILE + q * JT;
  }
  const float2* pxyI = pxy + ((m == 1) ? n : 0);
  const float* puI = pu + ((m == 1) ? n : 0);
  const float2* pxyJ = pxy + ((m == 0) ? 0 : n);
  const float* puJ = pu + ((m == 0) ? 0 : n);

  float cx = 0.f, cy = 0.f, cx2 = 0.f, cy2 = 0.f, cc = 0.f;
  if (m == 2) {
    slot_reduce(slot, smean);  // wave 0; consumed after the barrier below
  }

  float s0 = __expf(log_sigmas[0]);
  float s1 = __expf(log_sigmas[1]);
  float s2 = __expf(log_sigmas[2]);
  float rr0 = (s2 * s2) / (s0 * s0);
  float rr1 = (s2 * s2) / (s1 * s1);
  bool fast = (fabsf(rr0 - 16.f) <= 0.016f) && (fabsf(rr1 - 4.f) <= 0.004f);

  if (m == 2) {
    __syncthreads();
    cx = (float)(smean[2] / smean[0] - smean[6] / smean[4]);
    cy = (float)(smean[3] / smean[0] - smean[7] / smean[4]);
    cx2 = 2.f * cx;
    cy2 = 2.f * cy;
    cc = cx * cx + cy * cy;
  }

  if (threadIdx.x < JT) {
    float2 v = pxyJ[j0 + threadIdx.x];
    sx[threadIdx.x] = v.x;
    sy[threadIdx.x] = v.y;
    su[threadIdx.x] = puJ[j0 + threadIdx.x];
    if (m == 2) snb[threadIdx.x] = -fmaf(cx2, v.x, cy2 * v.y);  // -beta_j
  }
  __syncthreads();

  int i0 = it * ITILE + threadIdx.x;
  v2f xi2[4], yi2[4], al2[4];
  float u[4];
#pragma unroll
  for (int i = 0; i < 4; ++i) {
    float2 P = pxyI[i0 + i * 256];
    u[i] = puI[i0 + i * 256];
    float xv = P.x, yv = P.y, alv = 0.f;
    if (m == 2) {  // center i-side; alpha recovers uncentered distance
      xv -= cx;
      yv -= cy;
      alv = fmaf(cx2, xv, cy2 * yv) + cc;
    }
    xi2[i] = (v2f){xv, xv};
    yi2[i] = (v2f){yv, yv};
    al2[i] = (v2f){alv, alv};
  }

  v2f a0[4] = {}, a1[4] = {}, a2[4] = {};
  float sd = 0.f, sq = 0.f;
  if (m == 2) {
    if (fast)
      tile_loop<true, true>(sx, sy, su, snb, xi2, yi2, al2, rr0, rr1, a0, a1,
                            a2, sd, sq);
    else
      tile_loop<true, false>(sx, sy, su, snb, xi2, yi2, al2, rr0, rr1, a0, a1,
                             a2, sd, sq);
  } else {
    if (fast)
      tile_loop<false, true>(sx, sy, su, snb, xi2, yi2, al2, rr0, rr1, a0, a1,
                             a2, sd, sq);
    else
      tile_loop<false, false>(sx, sy, su, snb, xi2, yi2, al2, rr0, rr1, a0,
                              a1, a2, sd, sq);
  }

  double wgt = (m != 2 && jt != it) ? 2.0 : 1.0;  // symmetric off-diag tiles
  double c0 = 0.0, c1 = 0.0, c2 = 0.0;
#pragma unroll
  for (int i = 0; i < 4; ++i) {
    c0 += (double)u[i] * (double)(a0[i].x + a0[i].y);
    c1 += (double)u[i] * (double)(a1[i].x + a1[i].y);
    c2 += (double)u[i] * (double)(a2[i].x + a2[i].y);
  }
  double r0 = bred(c0, sm) * wgt;
  double r1 = bred(c1, sm) * wgt;
  double r2d = bred(c2, sm) * wgt;
  double* prow = (m == 0) ? paa : (m == 1) ? pbb : pab;
  int stride = (m == 2) ? NJOB_AB : NJOB_TRI;
  if (threadIdx.x == 0) {
    prow[0 * stride + pidx] = r0;
    prow[1 * stride + pidx] = r1;
    prow[2 * stride + pidx] = r2d;
  }
  if (m == 2) {
    double rsd = bred((double)sd, sm);
    double rsq = bred((double)sq, sm);
    if (threadIdx.x == 0) {
      psd[pidx] = rsd;
      psq[pidx] = rsq;
    }
  }

  // ---- last-block final reduction (ticket + device fence) ----
  if (threadIdx.x == 0) {
    __threadfence();
    unsigned old = atomicAdd(fctr, 1u);
    lastf = (old == NBLK - 1) ? 1 : 0;
  }
  __syncthreads();
  if (!lastf) return;
  __threadfence();

  slot_reduce(slot, smean);
  __syncthreads();
  int t = threadIdx.x;
  double vaa[3], vbb[3], vab[3];
  for (int s = 0; s < 3; ++s) {
    const double* pa = paa + s * NJOB_TRI;
    const double* pb = pbb + s * NJOB_TRI;
    const double* pc = pab + s * NJOB_AB;
    double va = pa[t] + pa[t + 256] + ((t < 64) ? pa[t + 512] : 0.0);
    double vb = pb[t] + pb[t + 256] + ((t < 64) ? pb[t + 512] : 0.0);
    double vc = pc[t] + pc[t + 256] + pc[t + 512] + pc[t + 768];
    vaa[s] = bred(va, sm);
    vbb[s] = bred(vb, sm);
    vab[s] = bred(vc, sm);
  }
  double sdt = bred(psd[t] + psd[t + 256] + psd[t + 512] + psd[t + 768], sm);
  double sqt = bred(psq[t] + psq[t + 256] + psq[t + 512] + psq[t + 768], sm);

  if (threadIdx.x == 0) {
    double Sb = smean[0], Qb = smean[1], St = smean[4], Qt = smean[5];
    double pband[3];
    for (int s = 0; s < 3; ++s)
      pband[s] = vaa[s] / (Sb * Sb) + vbb[s] / (St * St) -
                 2.0 * vab[s] / (Sb * St);
    double s2d = (double)s2;
    double r2sq = (double)L2E / (2.0 * s2d * s2d);
    double sd_real = sdt / sqrt(r2sq);
    double sq_real = sqt / r2sq;
    double NN = (double)n;
    double NM = NN * NN;
    double mean_d = sd_real / NM;
    double var_d = (sq_real - sd_real * sd_real / NM) / (NM - 1.0);
    double wv = (Qb / (Sb * Sb) - 1.0 / NN) / (NN - 1.0) +
                (Qt / (St * St) - 1.0 / NN) / (NN - 1.0);
    float st[4] = {(float)mean_d, (float)var_d, 0.f, (float)wv};
    float gl[3] = {g_b2[0], g_b2[1], g_b2[2]};
    for (int k = 0; k < 32; ++k) {
      float h = g_b1[k];
      for (int c = 0; c < 4; ++c) h = fmaf(st[c], g_w1[c * 32 + k], h);
      h = fmaxf(h, 0.f);
      for (int s = 0; s < 3; ++s) gl[s] = fmaf(h, g_w2[k * 3 + s], gl[s]);
    }
    float gw[3];
    float gsum = 0.f;
    for (int s = 0; s < 3; ++s) {
      gw[s] = fmaxf(gl[s], 0.f) + log1pf(__expf(-fabsf(gl[s])));
      gsum += gw[s];
    }
    double r = 0.0;
    for (int s = 0; s < 3; ++s) r += (double)(gw[s] / gsum) * pband[s];
    out[0] = (float)(r + (double)bias[0]);
  }
}

extern "C" void kernel_launch(void* const* d_in, const int* in_sizes, int n_in,
                              void* d_out, int out_size, void* d_ws,
                              size_t ws_size, hipStream_t stream) {
  const float* base = (const float*)d_in[0];
  const float* target = (const float*)d_in[1];
  const float* log_sigmas = (const float*)d_in[2];
  const float* log_scale = (const float*)d_in[3];
  const float* wn_w1 = (const float*)d_in[4];
  const float* wn_b1 = (const float*)d_in[5];
  const float* wn_w2 = (const float*)d_in[6];
  const float* wn_b2 = (const float*)d_in[7];
  const float* g_w1 = (const float*)d_in[8];
  const float* g_b1 = (const float*)d_in[9];
  const float* g_w2 = (const float*)d_in[10];
  const float* g_b2 = (const float*)d_in[11];
  const float* bias = (const float*)d_in[12];
  int n = in_sizes[0] / 2;  // 8192

  double* dbase = (double*)d_ws;
  double* slot = dbase;                // 64*4 = 256
  double* paa = dbase + 256;           // 3*576
  double* pbb = paa + 3 * NJOB_TRI;    // 3*576
  double* pab = pbb + 3 * NJOB_TRI;    // 3*1024
  double* psd = pab + 3 * NJOB_AB;     // 1024
  double* psq = psd + NJOB_AB;         // 1024
  double* dend = psq + NJOB_AB;
  float2* pxy = (float2*)dend;         // 2n
  float* pu = (float*)(pxy + 2 * n);   // 2n
  unsigned* fctr = (unsigned*)(pu + 2 * n);

  prep_kernel<<<(2 * n) / 256, 256, 0, stream>>>(
      base, target, log_sigmas, log_scale, wn_w1, wn_b1, wn_w2, wn_b2, pxy, pu,
      slot, fctr, n);
  pair_kernel<<<NBLK, 256, 0, stream>>>(pxy, pu, slot, paa, pbb, pab, psd, psq,
                                        fctr, log_sigmas, g_w1, g_b1, g_w2,
                                        g_b2, bias, (float*)d_out, n);
}